// Round 6
// baseline (287.525 us; speedup 1.0000x reference)
//
#include <hip/hip_runtime.h>
#include <math.h>

#define N_NODES 50000
#define N_EDGES 800000
#define BUCKET 64
#define SCAT_BLKS 196   // 100000 threads, 8 edges each
#define GEMM_BLKS 196   // ceil(3125 row-tiles / 16)
// F_IN = HID = 128, C = 40

typedef __attribute__((ext_vector_type(8))) short short8;
typedef __attribute__((ext_vector_type(4))) float f32x4;

__device__ __forceinline__ ushort f2bf(float f) {
    union { float f; uint u; } v; v.f = f;
    uint r = v.u + 0x7FFFu + ((v.u >> 16) & 1u);  // RNE
    return (ushort)(r >> 16);
}
__device__ __forceinline__ float bflo(uint p) {
    union { uint u; float f; } v; v.u = p << 16; return v.f;
}
__device__ __forceinline__ float bfhi(uint p) {
    union { uint u; float f; } v; v.u = p & 0xFFFF0000u; return v.f;
}

// ---------------- fused: bucketed scatter + gemm1 (MFMA, fp32->bf16 inline) ----------------
// blocks [0, SCAT_BLKS): scatter 8 edges/thread into 64-slot ushort buckets
// blocks [SCAT_BLKS, SCAT_BLKS+GEMM_BLKS): Y = cvt(x) @ W1 (bf16 out)
__global__ __launch_bounds__(512) void fused_gemm1_scatter_k(
        const float* __restrict__ Af, const float* __restrict__ W, ushort* __restrict__ Y,
        const int* __restrict__ src, const int* __restrict__ dst,
        int* __restrict__ cnt, ushort* __restrict__ colb) {
    constexpr int NT = 8;
    __shared__ ushort sB[4 * NT * 64 * 8];
    const int tid = threadIdx.x;

    if (blockIdx.x < SCAT_BLKS) {
        const int t = blockIdx.x * 512 + tid;
        if (t >= N_EDGES / 8) return;
        const int4* s32 = reinterpret_cast<const int4*>(src);
        const int4* d32 = reinterpret_cast<const int4*>(dst);
        const int4 sa = s32[2 * t], sb = s32[2 * t + 1];
        const int4 da = d32[2 * t], db = d32[2 * t + 1];
        int p0 = atomicAdd(&cnt[da.x], 1);
        int p1 = atomicAdd(&cnt[da.y], 1);
        int p2 = atomicAdd(&cnt[da.z], 1);
        int p3 = atomicAdd(&cnt[da.w], 1);
        int p4 = atomicAdd(&cnt[db.x], 1);
        int p5 = atomicAdd(&cnt[db.y], 1);
        int p6 = atomicAdd(&cnt[db.z], 1);
        int p7 = atomicAdd(&cnt[db.w], 1);
        colb[(size_t)da.x * BUCKET + p0] = (ushort)sa.x;
        colb[(size_t)da.y * BUCKET + p1] = (ushort)sa.y;
        colb[(size_t)da.z * BUCKET + p2] = (ushort)sa.z;
        colb[(size_t)da.w * BUCKET + p3] = (ushort)sa.w;
        colb[(size_t)db.x * BUCKET + p4] = (ushort)sb.x;
        colb[(size_t)db.y * BUCKET + p5] = (ushort)sb.y;
        colb[(size_t)db.z * BUCKET + p6] = (ushort)sb.z;
        colb[(size_t)db.w * BUCKET + p7] = (ushort)sb.w;
        return;
    }

    // ---- gemm role ----
    constexpr int FP = NT * 16;
    for (int i = tid; i < 128 * FP; i += 512) {
        const int k = i / FP, n = i % FP;
        const int s = k >> 5, r2 = (k >> 3) & 3, j = k & 7;
        const int t = n >> 4, nl = n & 15;
        const int l = r2 * 16 + nl;
        const int lp = (l & 56) | ((l + (l >> 3)) & 7);
        sB[(((s * NT + t) * 64) + lp) * 8 + j] = f2bf(W[k * 128 + n]);
    }
    __syncthreads();

    const int wid = tid >> 6, lane = tid & 63;
    const int lp = (lane & 56) | ((lane + (lane >> 3)) & 7);
    const int t0 = (blockIdx.x - SCAT_BLKS) * 16 + wid * 2;
    const int t1 = t0 + 1;
    const int t0c = min(t0, N_NODES / 16 - 1);
    const int t1c = min(t1, N_NODES / 16 - 1);

    f32x4 acc[2][NT];
#pragma unroll
    for (int u = 0; u < 2; u++)
#pragma unroll
        for (int t = 0; t < NT; t++) acc[u][t] = (f32x4){0.f, 0.f, 0.f, 0.f};

#pragma unroll
    for (int s = 0; s < 4; s++) {
        short8 a0, a1;
        const int ko = 32 * s + 8 * (lane >> 4);
        const float4* p0 = reinterpret_cast<const float4*>(Af + (size_t)(t0c * 16 + (lane & 15)) * 128 + ko);
        const float4* p1 = reinterpret_cast<const float4*>(Af + (size_t)(t1c * 16 + (lane & 15)) * 128 + ko);
        float4 u0 = p0[0], u1 = p0[1], v0 = p1[0], v1 = p1[1];
        a0[0] = f2bf(u0.x); a0[1] = f2bf(u0.y); a0[2] = f2bf(u0.z); a0[3] = f2bf(u0.w);
        a0[4] = f2bf(u1.x); a0[5] = f2bf(u1.y); a0[6] = f2bf(u1.z); a0[7] = f2bf(u1.w);
        a1[0] = f2bf(v0.x); a1[1] = f2bf(v0.y); a1[2] = f2bf(v0.z); a1[3] = f2bf(v0.w);
        a1[4] = f2bf(v1.x); a1[5] = f2bf(v1.y); a1[6] = f2bf(v1.z); a1[7] = f2bf(v1.w);
#pragma unroll
        for (int t = 0; t < NT; t++) {
            short8 b = *reinterpret_cast<const short8*>(&sB[(((s * NT + t) * 64) + lp) * 8]);
            acc[0][t] = __builtin_amdgcn_mfma_f32_16x16x32_bf16(a0, b, acc[0][t], 0, 0, 0);
            acc[1][t] = __builtin_amdgcn_mfma_f32_16x16x32_bf16(a1, b, acc[1][t], 0, 0, 0);
        }
    }

    const int rl = 4 * (lane >> 4), cl = lane & 15;
#pragma unroll
    for (int u = 0; u < 2; u++) {
        const int tile = u ? t1 : t0;
        if (tile >= N_NODES / 16) continue;
        const int row0 = tile * 16;
#pragma unroll
        for (int t = 0; t < NT; t++) {
            const int c = 16 * t + cl;
#pragma unroll
            for (int g = 0; g < 4; g++)
                Y[(size_t)(row0 + rl + g) * 128 + c] = f2bf(acc[u][t][g]);
        }
    }
}

// ---------------- fused gather + gemm: out = relu(Ahat @ XW + bias) @ W ----------------
// Block owns 32 nodes (2 row-tiles). Phase A: 8 waves gather 4 nodes each into
// XOR-swizzled LDS (h in bf16). Phase B: waves compute (tile, col-tile) units.
template <int NT>
__global__ __launch_bounds__(512) void gathergemm_k(const ushort* __restrict__ XW,
                                                    const int* __restrict__ cnt,
                                                    const ushort* __restrict__ colb,
                                                    const float* __restrict__ bias,
                                                    const float* __restrict__ W,
                                                    ushort* __restrict__ Y,
                                                    const int fout) {
    __shared__ ushort sB[4 * NT * 64 * 8];
    __shared__ uint sA[32 * 64];  // 32 rows x 128 bf16, XOR-swizzled (byte^=(r&7)<<4)
    const int tid = threadIdx.x;
    const int wid = tid >> 6, lane = tid & 63;

    // stage W fragments (no sync needed before gather: disjoint LDS, same threads)
    constexpr int FP = NT * 16;
    for (int i = tid; i < 128 * FP; i += 512) {
        const int k = i / FP, n = i % FP;
        const int s = k >> 5, r2 = (k >> 3) & 3, j = k & 7;
        const int t = n >> 4, nl = n & 15;
        const int l = r2 * 16 + nl;
        const int lpw = (l & 56) | ((l + (l >> 3)) & 7);
        sB[(((s * NT + t) * 64) + lpw) * 8 + j] = (n < fout) ? f2bf(W[k * fout + n]) : (ushort)0;
    }

    // ---- phase A: gather 4 nodes per wave ----
    const int row0 = blockIdx.x * 32;
    const uint* XW32 = reinterpret_cast<const uint*>(XW);  // row stride 64 uints
#pragma unroll
    for (int u = 0; u < 4; u++) {
        const int r = wid * 4 + u;
        const int node = min(row0 + r, N_NODES - 1);
        const int n = cnt[node];
        const float di = rsqrtf((float)(n + 1));
        const ushort4* bucket = reinterpret_cast<const ushort4*>(colb + (size_t)node * BUCKET);

        float a0 = 0.f, a1 = 0.f, b0 = 0.f, b1 = 0.f;
        float c0 = 0.f, c1 = 0.f, d0 = 0.f, d1 = 0.f;
        int e = 0;
        for (; e + 4 <= n; e += 4) {
            const ushort4 s4 = bucket[e >> 2];
            const float w0 = rsqrtf((float)(cnt[s4.x] + 1)) * di;
            const float w1 = rsqrtf((float)(cnt[s4.y] + 1)) * di;
            const float w2 = rsqrtf((float)(cnt[s4.z] + 1)) * di;
            const float w3 = rsqrtf((float)(cnt[s4.w] + 1)) * di;
            const uint p0 = XW32[(size_t)s4.x * 64 + lane];
            const uint p1 = XW32[(size_t)s4.y * 64 + lane];
            const uint p2 = XW32[(size_t)s4.z * 64 + lane];
            const uint p3 = XW32[(size_t)s4.w * 64 + lane];
            a0 = fmaf(bflo(p0), w0, a0); a1 = fmaf(bfhi(p0), w0, a1);
            b0 = fmaf(bflo(p1), w1, b0); b1 = fmaf(bfhi(p1), w1, b1);
            c0 = fmaf(bflo(p2), w2, c0); c1 = fmaf(bfhi(p2), w2, c1);
            d0 = fmaf(bflo(p3), w3, d0); d1 = fmaf(bfhi(p3), w3, d1);
        }
        for (; e < n; e++) {
            const ushort s = colb[(size_t)node * BUCKET + e];
            const float w = rsqrtf((float)(cnt[s] + 1)) * di;
            const uint p = XW32[(size_t)s * 64 + lane];
            a0 = fmaf(bflo(p), w, a0); a1 = fmaf(bfhi(p), w, a1);
        }
        const uint ps = XW32[(size_t)node * 64 + lane];
        const float ws = di * di;
        a0 = fmaxf(fmaf(bflo(ps), ws, (a0 + b0) + (c0 + d0)) + bias[2 * lane], 0.f);
        a1 = fmaxf(fmaf(bfhi(ps), ws, (a1 + b1) + (c1 + d1)) + bias[2 * lane + 1], 0.f);
        sA[r * 64 + (lane ^ ((r & 7) << 2))] = (uint)f2bf(a0) | ((uint)f2bf(a1) << 16);
    }
    __syncthreads();

    // ---- phase B: units = 2 tiles x NT col-tiles over waves ----
    if (NT == 3 && wid >= 6) return;  // 6 units only
    const int tile = wid & 1;
    const int ar = tile * 16 + (lane & 15);
    const int hi = lane >> 4;
    const int lp = (lane & 56) | ((lane + (lane >> 3)) & 7);
    constexpr int UPW = (NT == 8) ? 2 : 1;

    f32x4 acc[UPW];
#pragma unroll
    for (int i = 0; i < UPW; i++) acc[i] = (f32x4){0.f, 0.f, 0.f, 0.f};

#pragma unroll
    for (int s = 0; s < 4; s++) {
        short8 a = *reinterpret_cast<const short8*>(
            &sA[ar * 64 + ((16 * s + 4 * hi) ^ ((ar & 7) << 2))]);
#pragma unroll
        for (int i = 0; i < UPW; i++) {
            const int t = (wid >> 1) + i * 4;
            short8 b = *reinterpret_cast<const short8*>(&sB[(((s * NT + t) * 64) + lp) * 8]);
            acc[i] = __builtin_amdgcn_mfma_f32_16x16x32_bf16(a, b, acc[i], 0, 0, 0);
        }
    }

    const int rl = 4 * hi, cl = lane & 15;
#pragma unroll
    for (int i = 0; i < UPW; i++) {
        const int t = (wid >> 1) + i * 4;
        const int c = 16 * t + cl;
        if (c >= fout) continue;
#pragma unroll
        for (int g = 0; g < 4; g++) {
            const int row = row0 + tile * 16 + rl + g;
            if (row < N_NODES) Y[(size_t)row * fout + c] = f2bf(acc[i][g]);
        }
    }
}

// ---------------- layer 3: gather (F=40) + log-softmax, 3 edge-groups per wave ----------------
__global__ __launch_bounds__(256) void gather40_lsm_k(const ushort* __restrict__ XW,
                                                      const int* __restrict__ cnt,
                                                      const ushort* __restrict__ colb,
                                                      const float* __restrict__ bias,
                                                      float* __restrict__ out) {
    const int node = (blockIdx.x * 256 + threadIdx.x) >> 6;
    const int lane = threadIdx.x & 63;
    if (node >= N_NODES) return;
    const int g = lane < 20 ? 0 : (lane < 40 ? 1 : 2);
    const int ll = lane - g * 20;
    const int llc = min(ll, 19);
    const int n = cnt[node];
    const float di = rsqrtf((float)(n + 1));
    const uint* XW32 = reinterpret_cast<const uint*>(XW);  // row stride 20 uints

    float a0 = 0.f, a1 = 0.f;
    for (int e = g; e < n; e += 3) {
        const ushort s = colb[(size_t)node * BUCKET + e];
        const float w = rsqrtf((float)(cnt[s] + 1)) * di;
        const uint p = XW32[(size_t)s * 20 + llc];
        a0 = fmaf(bflo(p), w, a0); a1 = fmaf(bfhi(p), w, a1);
    }
    const float t1 = __shfl(a0, lane + 20), t2 = __shfl(a0, lane + 40);
    const float u1 = __shfl(a1, lane + 20), u2 = __shfl(a1, lane + 40);
    float v0 = -INFINITY, v1 = -INFINITY;
    if (lane < 20) {
        const float s0 = a0 + t1 + t2, s1 = a1 + u1 + u2;
        const uint ps = XW32[(size_t)node * 20 + lane];
        const float ws = di * di;
        v0 = fmaf(bflo(ps), ws, s0) + bias[2 * lane];
        v1 = fmaf(bfhi(ps), ws, s1) + bias[2 * lane + 1];
    }
    float m = fmaxf(v0, v1);
#pragma unroll
    for (int o = 32; o > 0; o >>= 1) m = fmaxf(m, __shfl_xor(m, o));
    float s = (lane < 20) ? (expf(v0 - m) + expf(v1 - m)) : 0.f;
#pragma unroll
    for (int o = 32; o > 0; o >>= 1) s += __shfl_xor(s, o);
    if (lane < 20) {
        const float ls = m + logf(s);
        float2 r; r.x = v0 - ls; r.y = v1 - ls;
        reinterpret_cast<float2*>(out)[(size_t)node * 20 + lane] = r;
    }
}

extern "C" void kernel_launch(void* const* d_in, const int* in_sizes, int n_in,
                              void* d_out, int out_size, void* d_ws, size_t ws_size,
                              hipStream_t stream) {
    const float* x  = (const float*)d_in[0];
    const float* W1 = (const float*)d_in[1];
    const float* b1 = (const float*)d_in[2];
    const float* W2 = (const float*)d_in[3];
    const float* b2 = (const float*)d_in[4];
    const float* W3 = (const float*)d_in[5];
    const float* b3 = (const float*)d_in[6];
    const int* ei   = (const int*)d_in[7];
    const int* srcp = ei;
    const int* dstp = ei + N_EDGES;
    float* out = (float*)d_out;

    // workspace: cnt[50176 int] colb[50000*64 ushort] B0[N*128 bf16] B1[N*128 bf16]
    int*    cnt  = (int*)d_ws;
    ushort* colb = (ushort*)(cnt + 50176);
    ushort* B0   = colb + (size_t)N_NODES * BUCKET;   // byte ofs 6600704, 16B aligned
    ushort* B1   = B0 + (size_t)N_NODES * 128;

    const int NB_W = (N_NODES * 64) / 256;     // 12500 (one wave per node)
    const int NB_GG = (N_NODES + 31) / 32;     // 1563 gathergemm blocks

    hipMemsetAsync(cnt, 0, 50176 * sizeof(int), stream);
    // scatter + gemm1 (independent; scatter blocks first — they're the long pole)
    fused_gemm1_scatter_k<<<SCAT_BLKS + GEMM_BLKS, 512, 0, stream>>>(
        x, W1, B1, srcp, dstp, cnt, colb);
    // h1 = relu(Ahat @ XW1 + b1); XW2 = h1 @ W2
    gathergemm_k<8><<<NB_GG, 512, 0, stream>>>(B1, cnt, colb, b1, W2, B0, 128);
    // h2 = relu(Ahat @ XW2 + b2); XW3 = h2 @ W3
    gathergemm_k<3><<<NB_GG, 512, 0, stream>>>(B0, cnt, colb, b2, W3, B1, 40);
    // logits = Ahat @ XW3 + b3; log-softmax -> out
    gather40_lsm_k<<<NB_W, 256, 0, stream>>>(B1, cnt, colb, b3, out);
}

// Round 7
// 270.317 us; speedup vs baseline: 1.0637x; 1.0637x over previous
//
#include <hip/hip_runtime.h>
#include <math.h>

#define N_NODES 50000
#define N_EDGES 800000
#define BUCKET 64
#define SCAT_BLKS 196   // 100352 threads, 8 edges each
#define GEMM_BLKS 196   // ceil(3125 row-tiles / 16)
// F_IN = HID = 128, C = 40

typedef __attribute__((ext_vector_type(8))) short short8;
typedef __attribute__((ext_vector_type(4))) float f32x4;

__device__ __forceinline__ ushort f2bf(float f) {
    union { float f; uint u; } v; v.f = f;
    uint r = v.u + 0x7FFFu + ((v.u >> 16) & 1u);  // RNE
    return (ushort)(r >> 16);
}
__device__ __forceinline__ float bflo(uint p) {
    union { uint u; float f; } v; v.u = p << 16; return v.f;
}
__device__ __forceinline__ float bfhi(uint p) {
    union { uint u; float f; } v; v.u = p & 0xFFFF0000u; return v.f;
}

// ---------------- fused: bucketed scatter + gemm1 (MFMA, fp32->bf16 inline) ----------------
__global__ __launch_bounds__(512) void fused_gemm1_scatter_k(
        const float* __restrict__ Af, const float* __restrict__ W, ushort* __restrict__ Y,
        const int* __restrict__ src, const int* __restrict__ dst,
        int* __restrict__ cnt, ushort* __restrict__ colb) {
    constexpr int NT = 8;
    __shared__ ushort sB[4 * NT * 64 * 8];
    const int tid = threadIdx.x;

    if (blockIdx.x < SCAT_BLKS) {
        const int t = blockIdx.x * 512 + tid;
        if (t >= N_EDGES / 8) return;
        const int4* s32 = reinterpret_cast<const int4*>(src);
        const int4* d32 = reinterpret_cast<const int4*>(dst);
        const int4 sa = s32[2 * t], sb = s32[2 * t + 1];
        const int4 da = d32[2 * t], db = d32[2 * t + 1];
        int p0 = atomicAdd(&cnt[da.x], 1);
        int p1 = atomicAdd(&cnt[da.y], 1);
        int p2 = atomicAdd(&cnt[da.z], 1);
        int p3 = atomicAdd(&cnt[da.w], 1);
        int p4 = atomicAdd(&cnt[db.x], 1);
        int p5 = atomicAdd(&cnt[db.y], 1);
        int p6 = atomicAdd(&cnt[db.z], 1);
        int p7 = atomicAdd(&cnt[db.w], 1);
        colb[(size_t)da.x * BUCKET + p0] = (ushort)sa.x;
        colb[(size_t)da.y * BUCKET + p1] = (ushort)sa.y;
        colb[(size_t)da.z * BUCKET + p2] = (ushort)sa.z;
        colb[(size_t)da.w * BUCKET + p3] = (ushort)sa.w;
        colb[(size_t)db.x * BUCKET + p4] = (ushort)sb.x;
        colb[(size_t)db.y * BUCKET + p5] = (ushort)sb.y;
        colb[(size_t)db.z * BUCKET + p6] = (ushort)sb.z;
        colb[(size_t)db.w * BUCKET + p7] = (ushort)sb.w;
        return;
    }

    // ---- gemm role: Y = cvt(x) @ W1, raw (no dinv scaling; scatter concurrent) ----
    constexpr int FP = NT * 16;
    for (int i = tid; i < 128 * FP; i += 512) {
        const int k = i / FP, n = i % FP;
        const int s = k >> 5, r2 = (k >> 3) & 3, j = k & 7;
        const int t = n >> 4, nl = n & 15;
        const int l = r2 * 16 + nl;
        const int lp = (l & 56) | ((l + (l >> 3)) & 7);
        sB[(((s * NT + t) * 64) + lp) * 8 + j] = f2bf(W[k * 128 + n]);
    }
    __syncthreads();

    const int wid = tid >> 6, lane = tid & 63;
    const int lp = (lane & 56) | ((lane + (lane >> 3)) & 7);
    const int t0 = (blockIdx.x - SCAT_BLKS) * 16 + wid * 2;
    const int t1 = t0 + 1;
    const int t0c = min(t0, N_NODES / 16 - 1);
    const int t1c = min(t1, N_NODES / 16 - 1);

    f32x4 acc[2][NT];
#pragma unroll
    for (int u = 0; u < 2; u++)
#pragma unroll
        for (int t = 0; t < NT; t++) acc[u][t] = (f32x4){0.f, 0.f, 0.f, 0.f};

#pragma unroll
    for (int s = 0; s < 4; s++) {
        short8 a0, a1;
        const int ko = 32 * s + 8 * (lane >> 4);
        const float4* p0 = reinterpret_cast<const float4*>(Af + (size_t)(t0c * 16 + (lane & 15)) * 128 + ko);
        const float4* p1 = reinterpret_cast<const float4*>(Af + (size_t)(t1c * 16 + (lane & 15)) * 128 + ko);
        float4 u0 = p0[0], u1 = p0[1], v0 = p1[0], v1 = p1[1];
        a0[0] = f2bf(u0.x); a0[1] = f2bf(u0.y); a0[2] = f2bf(u0.z); a0[3] = f2bf(u0.w);
        a0[4] = f2bf(u1.x); a0[5] = f2bf(u1.y); a0[6] = f2bf(u1.z); a0[7] = f2bf(u1.w);
        a1[0] = f2bf(v0.x); a1[1] = f2bf(v0.y); a1[2] = f2bf(v0.z); a1[3] = f2bf(v0.w);
        a1[4] = f2bf(v1.x); a1[5] = f2bf(v1.y); a1[6] = f2bf(v1.z); a1[7] = f2bf(v1.w);
#pragma unroll
        for (int t = 0; t < NT; t++) {
            short8 b = *reinterpret_cast<const short8*>(&sB[(((s * NT + t) * 64) + lp) * 8]);
            acc[0][t] = __builtin_amdgcn_mfma_f32_16x16x32_bf16(a0, b, acc[0][t], 0, 0, 0);
            acc[1][t] = __builtin_amdgcn_mfma_f32_16x16x32_bf16(a1, b, acc[1][t], 0, 0, 0);
        }
    }

    const int rl = 4 * (lane >> 4), cl = lane & 15;
#pragma unroll
    for (int u = 0; u < 2; u++) {
        const int tile = u ? t1 : t0;
        if (tile >= N_NODES / 16) continue;
        const int row0 = tile * 16;
#pragma unroll
        for (int t = 0; t < NT; t++) {
            const int c = 16 * t + cl;
#pragma unroll
            for (int g = 0; g < 4; g++)
                Y[(size_t)(row0 + rl + g) * 128 + c] = f2bf(acc[u][t][g]);
        }
    }
}

// ---------------- MFMA GEMM (layers 2,3) with dinv-scaled epilogue ----------------
// Y[row] = (A[row] @ W) * rsqrt(cnt[row]+1)   (bf16 out)
template <int NT>
__global__ __launch_bounds__(512) void gemm_scaled_k(const ushort* __restrict__ Ab,
                                                     const float* __restrict__ W,
                                                     const int* __restrict__ cnt,
                                                     ushort* __restrict__ Y,
                                                     const int fout) {
    __shared__ ushort sB[4 * NT * 64 * 8];
    const int tid = threadIdx.x;
    constexpr int FP = NT * 16;
    for (int i = tid; i < 128 * FP; i += 512) {
        const int k = i / FP, n = i % FP;
        const int s = k >> 5, r2 = (k >> 3) & 3, j = k & 7;
        const int t = n >> 4, nl = n & 15;
        const int l = r2 * 16 + nl;
        const int lp = (l & 56) | ((l + (l >> 3)) & 7);
        sB[(((s * NT + t) * 64) + lp) * 8 + j] = (n < fout) ? f2bf(W[k * fout + n]) : (ushort)0;
    }
    __syncthreads();

    const int wid = tid >> 6, lane = tid & 63;
    const int lp = (lane & 56) | ((lane + (lane >> 3)) & 7);
    const int t0 = blockIdx.x * 16 + wid * 2;
    const int t1 = t0 + 1;
    const int t0c = min(t0, N_NODES / 16 - 1);
    const int t1c = min(t1, N_NODES / 16 - 1);

    f32x4 acc[2][NT];
#pragma unroll
    for (int u = 0; u < 2; u++)
#pragma unroll
        for (int t = 0; t < NT; t++) acc[u][t] = (f32x4){0.f, 0.f, 0.f, 0.f};

#pragma unroll
    for (int s = 0; s < 4; s++) {
        const int ko = 32 * s + 8 * (lane >> 4);
        short8 a0 = *reinterpret_cast<const short8*>(Ab + (size_t)(t0c * 16 + (lane & 15)) * 128 + ko);
        short8 a1 = *reinterpret_cast<const short8*>(Ab + (size_t)(t1c * 16 + (lane & 15)) * 128 + ko);
#pragma unroll
        for (int t = 0; t < NT; t++) {
            short8 b = *reinterpret_cast<const short8*>(&sB[(((s * NT + t) * 64) + lp) * 8]);
            acc[0][t] = __builtin_amdgcn_mfma_f32_16x16x32_bf16(a0, b, acc[0][t], 0, 0, 0);
            acc[1][t] = __builtin_amdgcn_mfma_f32_16x16x32_bf16(a1, b, acc[1][t], 0, 0, 0);
        }
    }

    const int rl = 4 * (lane >> 4), cl = lane & 15;
#pragma unroll
    for (int u = 0; u < 2; u++) {
        const int tile = u ? t1 : t0;
        if (tile >= N_NODES / 16) continue;
        const int row0 = tile * 16;
#pragma unroll
        for (int g = 0; g < 4; g++) {
            const int row = row0 + rl + g;
            const float dr = rsqrtf((float)(cnt[row] + 1));
#pragma unroll
            for (int t = 0; t < NT; t++) {
                const int c = 16 * t + cl;
                if (NT == 3 && c >= fout) continue;
                Y[(size_t)row * fout + c] = f2bf(acc[u][t][g] * dr);
            }
        }
    }
}

// ---------------- layer-1 gather: weights via lane-parallel preload + shfl broadcast ----------------
// out[i] = relu( di*( sum_j dinv_j*XW[j] + di*XW[i] ) + b ),  di = rsqrt(cnt[i]+1)
__global__ __launch_bounds__(256) void gather1_k(const ushort* __restrict__ XW,
                                                 const int* __restrict__ cnt,
                                                 const ushort* __restrict__ colb,
                                                 const float* __restrict__ bias,
                                                 ushort* __restrict__ out) {
    const int node = (blockIdx.x * 256 + threadIdx.x) >> 6;
    const int lane = threadIdx.x & 63;
    if (node >= N_NODES) return;
    const int n = cnt[node];
    const float di = rsqrtf((float)(n + 1));
    // lane-parallel: lane l owns edge l's (src, weight)
    int sl = 0; float wl = 0.f;
    if (lane < n) {
        sl = colb[(size_t)node * BUCKET + lane];
        wl = rsqrtf((float)(cnt[sl] + 1));
    }
    const uint* XW32 = reinterpret_cast<const uint*>(XW);  // row stride 64 uints

    float a0 = 0.f, a1 = 0.f, b0 = 0.f, b1 = 0.f;
    float c0 = 0.f, c1 = 0.f, d0 = 0.f, d1 = 0.f;
    int e = 0;
    for (; e + 4 <= n; e += 4) {
        const int s0 = __shfl(sl, e),     s1 = __shfl(sl, e + 1);
        const int s2 = __shfl(sl, e + 2), s3 = __shfl(sl, e + 3);
        const float w0 = __shfl(wl, e),     w1 = __shfl(wl, e + 1);
        const float w2 = __shfl(wl, e + 2), w3 = __shfl(wl, e + 3);
        const uint p0 = XW32[(size_t)s0 * 64 + lane];
        const uint p1 = XW32[(size_t)s1 * 64 + lane];
        const uint p2 = XW32[(size_t)s2 * 64 + lane];
        const uint p3 = XW32[(size_t)s3 * 64 + lane];
        a0 = fmaf(bflo(p0), w0, a0); a1 = fmaf(bfhi(p0), w0, a1);
        b0 = fmaf(bflo(p1), w1, b0); b1 = fmaf(bfhi(p1), w1, b1);
        c0 = fmaf(bflo(p2), w2, c0); c1 = fmaf(bfhi(p2), w2, c1);
        d0 = fmaf(bflo(p3), w3, d0); d1 = fmaf(bfhi(p3), w3, d1);
    }
    for (; e < n; e++) {
        const int s = __shfl(sl, e);
        const float w = __shfl(wl, e);
        const uint p = XW32[(size_t)s * 64 + lane];
        a0 = fmaf(bflo(p), w, a0); a1 = fmaf(bfhi(p), w, a1);
    }
    const uint ps = XW32[(size_t)node * 64 + lane];
    float t0 = (a0 + b0) + (c0 + d0); t0 = fmaf(bflo(ps), di, t0);
    float t1 = (a1 + b1) + (c1 + d1); t1 = fmaf(bfhi(ps), di, t1);
    const float o0 = fmaxf(fmaf(di, t0, bias[2 * lane]), 0.f);
    const float o1 = fmaxf(fmaf(di, t1, bias[2 * lane + 1]), 0.f);
    reinterpret_cast<uint*>(out)[(size_t)node * 64 + lane] =
        (uint)f2bf(o0) | ((uint)f2bf(o1) << 16);
}

// ---------------- layers 2 gather: PURE ADD (input rows pre-scaled by dinv_j) ----------------
// out[i] = relu( di * ( sum_j XWn[j] + XWn[i] ) + b )
__global__ __launch_bounds__(256) void gather_add_k(const ushort* __restrict__ XWn,
                                                    const int* __restrict__ cnt,
                                                    const ushort* __restrict__ colb,
                                                    const float* __restrict__ bias,
                                                    ushort* __restrict__ out) {
    const int node = (blockIdx.x * 256 + threadIdx.x) >> 6;
    const int lane = threadIdx.x & 63;
    if (node >= N_NODES) return;
    const int n = cnt[node];
    const float di = rsqrtf((float)(n + 1));
    const ushort4* bucket = reinterpret_cast<const ushort4*>(colb + (size_t)node * BUCKET);
    const uint* XW32 = reinterpret_cast<const uint*>(XWn);  // row stride 64 uints

    float a0 = 0.f, a1 = 0.f, b0 = 0.f, b1 = 0.f;
    float c0 = 0.f, c1 = 0.f, d0 = 0.f, d1 = 0.f;
    int e = 0;
    for (; e + 4 <= n; e += 4) {
        const ushort4 s4 = bucket[e >> 2];
        const uint p0 = XW32[(size_t)s4.x * 64 + lane];
        const uint p1 = XW32[(size_t)s4.y * 64 + lane];
        const uint p2 = XW32[(size_t)s4.z * 64 + lane];
        const uint p3 = XW32[(size_t)s4.w * 64 + lane];
        a0 += bflo(p0); a1 += bfhi(p0);
        b0 += bflo(p1); b1 += bfhi(p1);
        c0 += bflo(p2); c1 += bfhi(p2);
        d0 += bflo(p3); d1 += bfhi(p3);
    }
    for (; e < n; e++) {
        const ushort s = colb[(size_t)node * BUCKET + e];
        const uint p = XW32[(size_t)s * 64 + lane];
        a0 += bflo(p); a1 += bfhi(p);
    }
    const uint ps = XW32[(size_t)node * 64 + lane];
    const float t0 = ((a0 + b0) + (c0 + d0)) + bflo(ps);
    const float t1 = ((a1 + b1) + (c1 + d1)) + bfhi(ps);
    const float o0 = fmaxf(fmaf(di, t0, bias[2 * lane]), 0.f);
    const float o1 = fmaxf(fmaf(di, t1, bias[2 * lane + 1]), 0.f);
    reinterpret_cast<uint*>(out)[(size_t)node * 64 + lane] =
        (uint)f2bf(o0) | ((uint)f2bf(o1) << 16);
}

// ---------------- layer 3: pure-add gather (F=40, pre-scaled) + log-softmax ----------------
__global__ __launch_bounds__(256) void gather40_lsm_k(const ushort* __restrict__ XWn,
                                                      const int* __restrict__ cnt,
                                                      const ushort* __restrict__ colb,
                                                      const float* __restrict__ bias,
                                                      float* __restrict__ out) {
    const int node = (blockIdx.x * 256 + threadIdx.x) >> 6;
    const int lane = threadIdx.x & 63;
    if (node >= N_NODES) return;
    const int g = lane < 20 ? 0 : (lane < 40 ? 1 : 2);
    const int ll = lane - g * 20;
    const int llc = min(ll, 19);
    const int n = cnt[node];
    const float di = rsqrtf((float)(n + 1));
    const uint* XW32 = reinterpret_cast<const uint*>(XWn);  // row stride 20 uints

    float a0 = 0.f, a1 = 0.f;
    for (int e = g; e < n; e += 3) {
        const ushort s = colb[(size_t)node * BUCKET + e];
        const uint p = XW32[(size_t)s * 20 + llc];
        a0 += bflo(p); a1 += bfhi(p);
    }
    const float t1 = __shfl(a0, lane + 20), t2 = __shfl(a0, lane + 40);
    const float u1 = __shfl(a1, lane + 20), u2 = __shfl(a1, lane + 40);
    float v0 = -INFINITY, v1 = -INFINITY;
    if (lane < 20) {
        const uint ps = XW32[(size_t)node * 20 + lane];
        v0 = fmaf(di, (a0 + t1 + t2) + bflo(ps), bias[2 * lane]);
        v1 = fmaf(di, (a1 + u1 + u2) + bfhi(ps), bias[2 * lane + 1]);
    }
    float m = fmaxf(v0, v1);
#pragma unroll
    for (int o = 32; o > 0; o >>= 1) m = fmaxf(m, __shfl_xor(m, o));
    float s = (lane < 20) ? (expf(v0 - m) + expf(v1 - m)) : 0.f;
#pragma unroll
    for (int o = 32; o > 0; o >>= 1) s += __shfl_xor(s, o);
    if (lane < 20) {
        const float ls = m + logf(s);
        float2 r; r.x = v0 - ls; r.y = v1 - ls;
        reinterpret_cast<float2*>(out)[(size_t)node * 20 + lane] = r;
    }
}

extern "C" void kernel_launch(void* const* d_in, const int* in_sizes, int n_in,
                              void* d_out, int out_size, void* d_ws, size_t ws_size,
                              hipStream_t stream) {
    const float* x  = (const float*)d_in[0];
    const float* W1 = (const float*)d_in[1];
    const float* b1 = (const float*)d_in[2];
    const float* W2 = (const float*)d_in[3];
    const float* b2 = (const float*)d_in[4];
    const float* W3 = (const float*)d_in[5];
    const float* b3 = (const float*)d_in[6];
    const int* ei   = (const int*)d_in[7];
    const int* srcp = ei;
    const int* dstp = ei + N_EDGES;
    float* out = (float*)d_out;

    // workspace: cnt[50176 int] colb[50000*64 ushort] B0[N*128 bf16] B1[N*128 bf16]
    int*    cnt  = (int*)d_ws;
    ushort* colb = (ushort*)(cnt + 50176);
    ushort* B0   = colb + (size_t)N_NODES * BUCKET;   // 16B aligned
    ushort* B1   = B0 + (size_t)N_NODES * 128;

    const int NB_W = (N_NODES * 64) / 256;   // 12500 (one wave per node)

    hipMemsetAsync(cnt, 0, 50176 * sizeof(int), stream);
    // scatter (latency-bound) overlapped with gemm1 (XW1 = cvt(x) @ W1, raw)
    fused_gemm1_scatter_k<<<SCAT_BLKS + GEMM_BLKS, 512, 0, stream>>>(
        x, W1, B1, srcp, dstp, cnt, colb);
    // h1 = relu(Ahat @ XW1 + b1)   (per-edge weights via lane-preload + shfl)
    gather1_k<<<NB_W, 256, 0, stream>>>(B1, cnt, colb, b1, B0);
    // XW2n = (h1 @ W2) * dinv[row]
    gemm_scaled_k<8><<<GEMM_BLKS, 512, 0, stream>>>(B0, W2, cnt, B1, 128);
    // h2 = relu(di * (sum XW2n + self) + b2)
    gather_add_k<<<NB_W, 256, 0, stream>>>(B1, cnt, colb, b2, B0);
    // XW3n = (h2 @ W3) * dinv[row]
    gemm_scaled_k<3><<<GEMM_BLKS, 512, 0, stream>>>(B0, W3, cnt, B1, 40);
    // logits + log-softmax
    gather40_lsm_k<<<NB_W, 256, 0, stream>>>(B1, cnt, colb, b3, out);
}

// Round 8
// 263.326 us; speedup vs baseline: 1.0919x; 1.0265x over previous
//
#include <hip/hip_runtime.h>
#include <math.h>

#define N_NODES 50000
#define N_EDGES 800000
#define BUCKET 64
#define SCAT_BLKS 392   // 8 dst-range groups x 49 chunk groups
#define QPG 4082        // int4-quads per chunk group (49*4082 >= 200000)
#define GEMM_BLKS 196   // ceil(3125 row-tiles / 16)
// F_IN = HID = 128, C = 40

typedef __attribute__((ext_vector_type(8))) short short8;
typedef __attribute__((ext_vector_type(4))) float f32x4;

__device__ __forceinline__ ushort f2bf(float f) {
    union { float f; uint u; } v; v.f = f;
    uint r = v.u + 0x7FFFu + ((v.u >> 16) & 1u);  // RNE
    return (ushort)(r >> 16);
}
__device__ __forceinline__ float bflo(uint p) {
    union { uint u; float f; } v; v.u = p << 16; return v.f;
}
__device__ __forceinline__ float bfhi(uint p) {
    union { uint u; float f; } v; v.u = p & 0xFFFF0000u; return v.f;
}

// ---------------- fused: range-partitioned scatter + gemm1 (MFMA, fp32->bf16 inline) ----------------
// scatter blocks [0, SCAT_BLKS): r = b&7 owns dst range [r*6250,(r+1)*6250) — aligned with
// de-facto XCD = bid%8 so bucket lines are single-XCD (no cross-L2 ping-pong). Correct regardless.
// gemm blocks [SCAT_BLKS, SCAT_BLKS+GEMM_BLKS): Y = cvt(x) @ W1 (bf16 out, raw rows)
__global__ __launch_bounds__(512) void fused_gemm1_scatter_k(
        const float* __restrict__ Af, const float* __restrict__ W, ushort* __restrict__ Y,
        const int* __restrict__ src, const int* __restrict__ dst,
        int* __restrict__ cnt, ushort* __restrict__ colb) {
    constexpr int NT = 8;
    __shared__ ushort sB[4 * NT * 64 * 8];
    const int tid = threadIdx.x;

    if (blockIdx.x < SCAT_BLKS) {
        const int r = blockIdx.x & 7;
        const int g = blockIdx.x >> 3;
        const int lo = r * 6250;
        const int4* s32 = reinterpret_cast<const int4*>(src);
        const int4* d32 = reinterpret_cast<const int4*>(dst);
        const int qbeg = g * QPG + tid;
        const int qend = min((g + 1) * QPG, N_EDGES / 4);
#pragma unroll
        for (int u = 0; u < 8; u++) {
            const int q = qbeg + u * 512;
            if (q < qend) {
                const int4 d4 = d32[q];
                const int4 s4 = s32[q];
                if ((uint)(d4.x - lo) < 6250u) {
                    int p = atomicAdd(&cnt[d4.x], 1);
                    colb[(size_t)d4.x * BUCKET + p] = (ushort)s4.x;
                }
                if ((uint)(d4.y - lo) < 6250u) {
                    int p = atomicAdd(&cnt[d4.y], 1);
                    colb[(size_t)d4.y * BUCKET + p] = (ushort)s4.y;
                }
                if ((uint)(d4.z - lo) < 6250u) {
                    int p = atomicAdd(&cnt[d4.z], 1);
                    colb[(size_t)d4.z * BUCKET + p] = (ushort)s4.z;
                }
                if ((uint)(d4.w - lo) < 6250u) {
                    int p = atomicAdd(&cnt[d4.w], 1);
                    colb[(size_t)d4.w * BUCKET + p] = (ushort)s4.w;
                }
            }
        }
        return;
    }

    // ---- gemm role: Y = cvt(x) @ W1, raw (no dinv scaling; scatter concurrent) ----
    constexpr int FP = NT * 16;
    for (int i = tid; i < 128 * FP; i += 512) {
        const int k = i / FP, n = i % FP;
        const int s = k >> 5, r2 = (k >> 3) & 3, j = k & 7;
        const int t = n >> 4, nl = n & 15;
        const int l = r2 * 16 + nl;
        const int lp = (l & 56) | ((l + (l >> 3)) & 7);
        sB[(((s * NT + t) * 64) + lp) * 8 + j] = f2bf(W[k * 128 + n]);
    }
    __syncthreads();

    const int wid = tid >> 6, lane = tid & 63;
    const int lp = (lane & 56) | ((lane + (lane >> 3)) & 7);
    const int t0 = (blockIdx.x - SCAT_BLKS) * 16 + wid * 2;
    const int t1 = t0 + 1;
    const int t0c = min(t0, N_NODES / 16 - 1);
    const int t1c = min(t1, N_NODES / 16 - 1);

    f32x4 acc[2][NT];
#pragma unroll
    for (int u = 0; u < 2; u++)
#pragma unroll
        for (int t = 0; t < NT; t++) acc[u][t] = (f32x4){0.f, 0.f, 0.f, 0.f};

#pragma unroll
    for (int s = 0; s < 4; s++) {
        short8 a0, a1;
        const int ko = 32 * s + 8 * (lane >> 4);
        const float4* p0 = reinterpret_cast<const float4*>(Af + (size_t)(t0c * 16 + (lane & 15)) * 128 + ko);
        const float4* p1 = reinterpret_cast<const float4*>(Af + (size_t)(t1c * 16 + (lane & 15)) * 128 + ko);
        float4 u0 = p0[0], u1 = p0[1], v0 = p1[0], v1 = p1[1];
        a0[0] = f2bf(u0.x); a0[1] = f2bf(u0.y); a0[2] = f2bf(u0.z); a0[3] = f2bf(u0.w);
        a0[4] = f2bf(u1.x); a0[5] = f2bf(u1.y); a0[6] = f2bf(u1.z); a0[7] = f2bf(u1.w);
        a1[0] = f2bf(v0.x); a1[1] = f2bf(v0.y); a1[2] = f2bf(v0.z); a1[3] = f2bf(v0.w);
        a1[4] = f2bf(v1.x); a1[5] = f2bf(v1.y); a1[6] = f2bf(v1.z); a1[7] = f2bf(v1.w);
#pragma unroll
        for (int t = 0; t < NT; t++) {
            short8 b = *reinterpret_cast<const short8*>(&sB[(((s * NT + t) * 64) + lp) * 8]);
            acc[0][t] = __builtin_amdgcn_mfma_f32_16x16x32_bf16(a0, b, acc[0][t], 0, 0, 0);
            acc[1][t] = __builtin_amdgcn_mfma_f32_16x16x32_bf16(a1, b, acc[1][t], 0, 0, 0);
        }
    }

    const int rl = 4 * (lane >> 4), cl = lane & 15;
#pragma unroll
    for (int u = 0; u < 2; u++) {
        const int tile = u ? t1 : t0;
        if (tile >= N_NODES / 16) continue;
        const int row0 = tile * 16;
#pragma unroll
        for (int t = 0; t < NT; t++) {
            const int c = 16 * t + cl;
#pragma unroll
            for (int g = 0; g < 4; g++)
                Y[(size_t)(row0 + rl + g) * 128 + c] = f2bf(acc[u][t][g]);
        }
    }
}

// ---------------- MFMA GEMM (layers 2,3) with dinv-scaled epilogue ----------------
// Y[row] = (A[row] @ W) * rsqrt(cnt[row]+1)   (bf16 out)
template <int NT>
__global__ __launch_bounds__(512) void gemm_scaled_k(const ushort* __restrict__ Ab,
                                                     const float* __restrict__ W,
                                                     const int* __restrict__ cnt,
                                                     ushort* __restrict__ Y,
                                                     const int fout) {
    __shared__ ushort sB[4 * NT * 64 * 8];
    const int tid = threadIdx.x;
    constexpr int FP = NT * 16;
    for (int i = tid; i < 128 * FP; i += 512) {
        const int k = i / FP, n = i % FP;
        const int s = k >> 5, r2 = (k >> 3) & 3, j = k & 7;
        const int t = n >> 4, nl = n & 15;
        const int l = r2 * 16 + nl;
        const int lp = (l & 56) | ((l + (l >> 3)) & 7);
        sB[(((s * NT + t) * 64) + lp) * 8 + j] = (n < fout) ? f2bf(W[k * fout + n]) : (ushort)0;
    }
    __syncthreads();

    const int wid = tid >> 6, lane = tid & 63;
    const int lp = (lane & 56) | ((lane + (lane >> 3)) & 7);
    const int t0 = blockIdx.x * 16 + wid * 2;
    const int t1 = t0 + 1;
    const int t0c = min(t0, N_NODES / 16 - 1);
    const int t1c = min(t1, N_NODES / 16 - 1);

    f32x4 acc[2][NT];
#pragma unroll
    for (int u = 0; u < 2; u++)
#pragma unroll
        for (int t = 0; t < NT; t++) acc[u][t] = (f32x4){0.f, 0.f, 0.f, 0.f};

#pragma unroll
    for (int s = 0; s < 4; s++) {
        const int ko = 32 * s + 8 * (lane >> 4);
        short8 a0 = *reinterpret_cast<const short8*>(Ab + (size_t)(t0c * 16 + (lane & 15)) * 128 + ko);
        short8 a1 = *reinterpret_cast<const short8*>(Ab + (size_t)(t1c * 16 + (lane & 15)) * 128 + ko);
#pragma unroll
        for (int t = 0; t < NT; t++) {
            short8 b = *reinterpret_cast<const short8*>(&sB[(((s * NT + t) * 64) + lp) * 8]);
            acc[0][t] = __builtin_amdgcn_mfma_f32_16x16x32_bf16(a0, b, acc[0][t], 0, 0, 0);
            acc[1][t] = __builtin_amdgcn_mfma_f32_16x16x32_bf16(a1, b, acc[1][t], 0, 0, 0);
        }
    }

    const int rl = 4 * (lane >> 4), cl = lane & 15;
#pragma unroll
    for (int u = 0; u < 2; u++) {
        const int tile = u ? t1 : t0;
        if (tile >= N_NODES / 16) continue;
        const int row0 = tile * 16;
#pragma unroll
        for (int g = 0; g < 4; g++) {
            const int row = row0 + rl + g;
            const float dr = rsqrtf((float)(cnt[row] + 1));
#pragma unroll
            for (int t = 0; t < NT; t++) {
                const int c = 16 * t + cl;
                if (NT == 3 && c >= fout) continue;
                Y[(size_t)row * fout + c] = f2bf(acc[u][t][g] * dr);
            }
        }
    }
}

// ---------------- layer-1 gather: weights via lane-parallel preload + shfl broadcast ----------------
__global__ __launch_bounds__(256) void gather1_k(const ushort* __restrict__ XW,
                                                 const int* __restrict__ cnt,
                                                 const ushort* __restrict__ colb,
                                                 const float* __restrict__ bias,
                                                 ushort* __restrict__ out) {
    const int node = (blockIdx.x * 256 + threadIdx.x) >> 6;
    const int lane = threadIdx.x & 63;
    if (node >= N_NODES) return;
    const int n = cnt[node];
    const float di = rsqrtf((float)(n + 1));
    int sl = 0; float wl = 0.f;
    if (lane < n) {
        sl = colb[(size_t)node * BUCKET + lane];
        wl = rsqrtf((float)(cnt[sl] + 1));
    }
    const uint* XW32 = reinterpret_cast<const uint*>(XW);  // row stride 64 uints

    float a0 = 0.f, a1 = 0.f, b0 = 0.f, b1 = 0.f;
    float c0 = 0.f, c1 = 0.f, d0 = 0.f, d1 = 0.f;
    int e = 0;
    for (; e + 4 <= n; e += 4) {
        const int s0 = __shfl(sl, e),     s1 = __shfl(sl, e + 1);
        const int s2 = __shfl(sl, e + 2), s3 = __shfl(sl, e + 3);
        const float w0 = __shfl(wl, e),     w1 = __shfl(wl, e + 1);
        const float w2 = __shfl(wl, e + 2), w3 = __shfl(wl, e + 3);
        const uint p0 = XW32[(size_t)s0 * 64 + lane];
        const uint p1 = XW32[(size_t)s1 * 64 + lane];
        const uint p2 = XW32[(size_t)s2 * 64 + lane];
        const uint p3 = XW32[(size_t)s3 * 64 + lane];
        a0 = fmaf(bflo(p0), w0, a0); a1 = fmaf(bfhi(p0), w0, a1);
        b0 = fmaf(bflo(p1), w1, b0); b1 = fmaf(bfhi(p1), w1, b1);
        c0 = fmaf(bflo(p2), w2, c0); c1 = fmaf(bfhi(p2), w2, c1);
        d0 = fmaf(bflo(p3), w3, d0); d1 = fmaf(bfhi(p3), w3, d1);
    }
    for (; e < n; e++) {
        const int s = __shfl(sl, e);
        const float w = __shfl(wl, e);
        const uint p = XW32[(size_t)s * 64 + lane];
        a0 = fmaf(bflo(p), w, a0); a1 = fmaf(bfhi(p), w, a1);
    }
    const uint ps = XW32[(size_t)node * 64 + lane];
    float t0 = (a0 + b0) + (c0 + d0); t0 = fmaf(bflo(ps), di, t0);
    float t1 = (a1 + b1) + (c1 + d1); t1 = fmaf(bfhi(ps), di, t1);
    const float o0 = fmaxf(fmaf(di, t0, bias[2 * lane]), 0.f);
    const float o1 = fmaxf(fmaf(di, t1, bias[2 * lane + 1]), 0.f);
    reinterpret_cast<uint*>(out)[(size_t)node * 64 + lane] =
        (uint)f2bf(o0) | ((uint)f2bf(o1) << 16);
}

// ---------------- layer-2 gather: PURE ADD (input rows pre-scaled by dinv_j) ----------------
__global__ __launch_bounds__(256) void gather_add_k(const ushort* __restrict__ XWn,
                                                    const int* __restrict__ cnt,
                                                    const ushort* __restrict__ colb,
                                                    const float* __restrict__ bias,
                                                    ushort* __restrict__ out) {
    const int node = (blockIdx.x * 256 + threadIdx.x) >> 6;
    const int lane = threadIdx.x & 63;
    if (node >= N_NODES) return;
    const int n = cnt[node];
    const float di = rsqrtf((float)(n + 1));
    const ushort4* bucket = reinterpret_cast<const ushort4*>(colb + (size_t)node * BUCKET);
    const uint* XW32 = reinterpret_cast<const uint*>(XWn);  // row stride 64 uints

    float a0 = 0.f, a1 = 0.f, b0 = 0.f, b1 = 0.f;
    float c0 = 0.f, c1 = 0.f, d0 = 0.f, d1 = 0.f;
    int e = 0;
    for (; e + 4 <= n; e += 4) {
        const ushort4 s4 = bucket[e >> 2];
        const uint p0 = XW32[(size_t)s4.x * 64 + lane];
        const uint p1 = XW32[(size_t)s4.y * 64 + lane];
        const uint p2 = XW32[(size_t)s4.z * 64 + lane];
        const uint p3 = XW32[(size_t)s4.w * 64 + lane];
        a0 += bflo(p0); a1 += bfhi(p0);
        b0 += bflo(p1); b1 += bfhi(p1);
        c0 += bflo(p2); c1 += bfhi(p2);
        d0 += bflo(p3); d1 += bfhi(p3);
    }
    for (; e < n; e++) {
        const ushort s = colb[(size_t)node * BUCKET + e];
        const uint p = XW32[(size_t)s * 64 + lane];
        a0 += bflo(p); a1 += bfhi(p);
    }
    const uint ps = XW32[(size_t)node * 64 + lane];
    const float t0 = ((a0 + b0) + (c0 + d0)) + bflo(ps);
    const float t1 = ((a1 + b1) + (c1 + d1)) + bfhi(ps);
    const float o0 = fmaxf(fmaf(di, t0, bias[2 * lane]), 0.f);
    const float o1 = fmaxf(fmaf(di, t1, bias[2 * lane + 1]), 0.f);
    reinterpret_cast<uint*>(out)[(size_t)node * 64 + lane] =
        (uint)f2bf(o0) | ((uint)f2bf(o1) << 16);
}

// ---------------- layer 3: pure-add gather (F=40, pre-scaled) + log-softmax ----------------
__global__ __launch_bounds__(256) void gather40_lsm_k(const ushort* __restrict__ XWn,
                                                      const int* __restrict__ cnt,
                                                      const ushort* __restrict__ colb,
                                                      const float* __restrict__ bias,
                                                      float* __restrict__ out) {
    const int node = (blockIdx.x * 256 + threadIdx.x) >> 6;
    const int lane = threadIdx.x & 63;
    if (node >= N_NODES) return;
    const int g = lane < 20 ? 0 : (lane < 40 ? 1 : 2);
    const int ll = lane - g * 20;
    const int llc = min(ll, 19);
    const int n = cnt[node];
    const float di = rsqrtf((float)(n + 1));
    const uint* XW32 = reinterpret_cast<const uint*>(XWn);  // row stride 20 uints

    float a0 = 0.f, a1 = 0.f;
    for (int e = g; e < n; e += 3) {
        const ushort s = colb[(size_t)node * BUCKET + e];
        const uint p = XW32[(size_t)s * 20 + llc];
        a0 += bflo(p); a1 += bfhi(p);
    }
    const float t1 = __shfl(a0, lane + 20), t2 = __shfl(a0, lane + 40);
    const float u1 = __shfl(a1, lane + 20), u2 = __shfl(a1, lane + 40);
    float v0 = -INFINITY, v1 = -INFINITY;
    if (lane < 20) {
        const uint ps = XW32[(size_t)node * 20 + lane];
        v0 = fmaf(di, (a0 + t1 + t2) + bflo(ps), bias[2 * lane]);
        v1 = fmaf(di, (a1 + u1 + u2) + bfhi(ps), bias[2 * lane + 1]);
    }
    float m = fmaxf(v0, v1);
#pragma unroll
    for (int o = 32; o > 0; o >>= 1) m = fmaxf(m, __shfl_xor(m, o));
    float s = (lane < 20) ? (expf(v0 - m) + expf(v1 - m)) : 0.f;
#pragma unroll
    for (int o = 32; o > 0; o >>= 1) s += __shfl_xor(s, o);
    if (lane < 20) {
        const float ls = m + logf(s);
        float2 r; r.x = v0 - ls; r.y = v1 - ls;
        reinterpret_cast<float2*>(out)[(size_t)node * 20 + lane] = r;
    }
}

extern "C" void kernel_launch(void* const* d_in, const int* in_sizes, int n_in,
                              void* d_out, int out_size, void* d_ws, size_t ws_size,
                              hipStream_t stream) {
    const float* x  = (const float*)d_in[0];
    const float* W1 = (const float*)d_in[1];
    const float* b1 = (const float*)d_in[2];
    const float* W2 = (const float*)d_in[3];
    const float* b2 = (const float*)d_in[4];
    const float* W3 = (const float*)d_in[5];
    const float* b3 = (const float*)d_in[6];
    const int* ei   = (const int*)d_in[7];
    const int* srcp = ei;
    const int* dstp = ei + N_EDGES;
    float* out = (float*)d_out;

    // workspace: cnt[50176 int] colb[50000*64 ushort] B0[N*128 bf16] B1[N*128 bf16]
    int*    cnt  = (int*)d_ws;
    ushort* colb = (ushort*)(cnt + 50176);
    ushort* B0   = colb + (size_t)N_NODES * BUCKET;   // 16B aligned
    ushort* B1   = B0 + (size_t)N_NODES * 128;

    const int NB_W = (N_NODES * 64) / 256;   // 12500 (one wave per node)

    hipMemsetAsync(cnt, 0, 50176 * sizeof(int), stream);
    // range-partitioned scatter (XCD-local bucket lines) overlapped with gemm1
    fused_gemm1_scatter_k<<<SCAT_BLKS + GEMM_BLKS, 512, 0, stream>>>(
        x, W1, B1, srcp, dstp, cnt, colb);
    // h1 = relu(Ahat @ XW1 + b1)   (per-edge weights via lane-preload + shfl)
    gather1_k<<<NB_W, 256, 0, stream>>>(B1, cnt, colb, b1, B0);
    // XW2n = (h1 @ W2) * dinv[row]
    gemm_scaled_k<8><<<GEMM_BLKS, 512, 0, stream>>>(B0, W2, cnt, B1, 128);
    // h2 = relu(di * (sum XW2n + self) + b2)
    gather_add_k<<<NB_W, 256, 0, stream>>>(B1, cnt, colb, b2, B0);
    // XW3n = (h2 @ W3) * dinv[row]
    gemm_scaled_k<3><<<GEMM_BLKS, 512, 0, stream>>>(B0, W3, cnt, B1, 40);
    // logits + log-softmax
    gather40_lsm_k<<<NB_W, 256, 0, stream>>>(B1, cnt, colb, b3, out);
}